// Round 6
// baseline (410.675 us; speedup 1.0000x reference)
//
#include <hip/hip_runtime.h>

#define NT 512
#define SCL (1.0f / 8192.0f)
#define PI_F 3.14159265358979323846f

// XOR swizzle: bijective involution on [0,8192); spreads the power-of-2 strided
// trip accesses across banks. Applied at EVERY cb access.
__device__ __forceinline__ int P(int i) { return i ^ ((i >> 5) & 31); }

__device__ __forceinline__ float2 cmul(float2 a, float2 b) {
  return make_float2(a.x * b.x - a.y * b.y, a.x * b.y + a.y * b.x);
}
__device__ __forceinline__ float2 csqr(float2 a) {
  return make_float2(a.x * a.x - a.y * a.y, 2.f * a.x * a.y);
}
__device__ __forceinline__ float2 cadd(float2 a, float2 b) { return make_float2(a.x + b.x, a.y + b.y); }
__device__ __forceinline__ float2 csub(float2 a, float2 b) { return make_float2(a.x - b.x, a.y - b.y); }
__device__ __forceinline__ float2 cmuli (float2 a) { return make_float2(-a.y,  a.x); } // *(+i)
__device__ __forceinline__ float2 cmulmi(float2 a) { return make_float2( a.y, -a.x); } // *(-i)

constexpr float RT2 = 0.70710678118654752440f;
constexpr float CQ1 = 0.92387953251128675613f; // cos(pi/8)
constexpr float SQ1 = 0.38268343236508977173f; // sin(pi/8)
// C16[k] = W16^k = e^{-i pi k/8}
constexpr float C16x[8] = {1.f,  CQ1,  RT2,  SQ1, 0.f, -SQ1, -RT2, -CQ1};
constexpr float C16y[8] = {0.f, -SQ1, -RT2, -CQ1, -1.f, -CQ1, -RT2, -SQ1};
// C8[k] = W8^k = e^{-i pi k/4}
constexpr float C8x[4] = {1.f,  RT2, 0.f, -RT2};
constexpr float C8y[4] = {0.f, -RT2, -1.f, -RT2};

// In-register 16-point DIF, stages at register strides 8,4,2,1.
// Stage stride s uses twiddle b^{8/s} * W_{2s}^{j mod s}; UNIT means b == 1.
template<bool UNIT>
__device__ __forceinline__ void r16_fwd(float2* e, float2 b) {
  float2 b2, b4, b8, b4mi;
  if (!UNIT) { b2 = csqr(b); b4 = csqr(b2); b8 = csqr(b4); b4mi = cmulmi(b4); }
  #pragma unroll
  for (int j = 0; j < 8; ++j) {
    float2 u = e[j], v = e[j + 8];
    float2 d = csub(u, v);
    e[j] = cadd(u, v);
    if (UNIT) e[j + 8] = (j == 0) ? d : cmul(d, make_float2(C16x[j], C16y[j]));
    else {
      float2 tw = (j == 0) ? b : cmul(b, make_float2(C16x[j], C16y[j]));
      e[j + 8] = cmul(d, tw);
    }
  }
  #pragma unroll
  for (int o = 0; o < 16; o += 8) {
    #pragma unroll
    for (int j = 0; j < 4; ++j) {
      float2 u = e[o + j], v = e[o + j + 4];
      float2 d = csub(u, v);
      e[o + j] = cadd(u, v);
      if (UNIT) e[o + j + 4] = (j == 0) ? d : cmul(d, make_float2(C8x[j], C8y[j]));
      else {
        float2 tw = (j == 0) ? b2 : cmul(b2, make_float2(C8x[j], C8y[j]));
        e[o + j + 4] = cmul(d, tw);
      }
    }
  }
  #pragma unroll
  for (int o = 0; o < 16; o += 4) {
    #pragma unroll
    for (int j = 0; j < 2; ++j) {
      float2 u = e[o + j], v = e[o + j + 2];
      float2 d = csub(u, v);
      e[o + j] = cadd(u, v);
      if (UNIT) e[o + j + 2] = (j == 0) ? d : cmulmi(d);
      else      e[o + j + 2] = cmul(d, (j == 0) ? b4 : b4mi);
    }
  }
  #pragma unroll
  for (int o = 0; o < 16; o += 2) {
    float2 u = e[o], v = e[o + 1];
    float2 d = csub(u, v);
    e[o] = cadd(u, v);
    e[o + 1] = UNIT ? d : cmul(d, b8);
  }
}

// In-register 16-point DIT inverse, stages at register strides 1,2,4,8.
// Stage stride s uses twiddle g^{8/s} * conj(W_{2s})^{j mod s}; g = conj(beta).
template<bool UNIT>
__device__ __forceinline__ void r16_inv(float2* e, float2 g) {
  float2 g2, g4, g8, g4i;
  if (!UNIT) { g2 = csqr(g); g4 = csqr(g2); g8 = csqr(g4); g4i = cmuli(g4); }
  #pragma unroll
  for (int o = 0; o < 16; o += 2) {
    float2 t = UNIT ? e[o + 1] : cmul(e[o + 1], g8);
    float2 u = e[o];
    e[o] = cadd(u, t); e[o + 1] = csub(u, t);
  }
  #pragma unroll
  for (int o = 0; o < 16; o += 4) {
    #pragma unroll
    for (int j = 0; j < 2; ++j) {
      float2 v = e[o + j + 2];
      float2 t;
      if (UNIT) t = (j == 0) ? v : cmuli(v);
      else      t = cmul(v, (j == 0) ? g4 : g4i);
      float2 u = e[o + j];
      e[o + j] = cadd(u, t); e[o + j + 2] = csub(u, t);
    }
  }
  #pragma unroll
  for (int o = 0; o < 16; o += 8) {
    #pragma unroll
    for (int j = 0; j < 4; ++j) {
      float2 v = e[o + j + 4];
      float2 t;
      if (UNIT) t = (j == 0) ? v : cmul(v, make_float2(C8x[j], -C8y[j]));
      else      t = cmul(v, (j == 0) ? g2 : cmul(g2, make_float2(C8x[j], -C8y[j])));
      float2 u = e[o + j];
      e[o + j] = cadd(u, t); e[o + j + 4] = csub(u, t);
    }
  }
  #pragma unroll
  for (int j = 0; j < 8; ++j) {
    float2 v = e[j + 8];
    float2 t;
    if (UNIT) t = (j == 0) ? v : cmul(v, make_float2(C16x[j], -C16y[j]));
    else      t = cmul(v, (j == 0) ? g : cmul(g, make_float2(C16x[j], -C16y[j])));
    float2 u = e[j];
    e[j] = cadd(u, t); e[j + 8] = csub(u, t);
  }
}

__device__ __forceinline__ void trip_fwd(float2* cb, int base, int G, float2 b) {
  float2 e[16];
  #pragma unroll
  for (int j = 0; j < 16; ++j) e[j] = cb[P(base + G * j)];
  r16_fwd<false>(e, b);
  #pragma unroll
  for (int j = 0; j < 16; ++j) cb[P(base + G * j)] = e[j];
}

__device__ __forceinline__ void trip_inv(float2* cb, int base, int G, float2 g) {
  float2 e[16];
  #pragma unroll
  for (int j = 0; j < 16; ++j) e[j] = cb[P(base + G * j)];
  r16_inv<false>(e, g);
  #pragma unroll
  for (int j = 0; j < 16; ++j) cb[P(base + G * j)] = e[j];
}

// One workgroup per channel d. xT: (b, d, n) rows of 4096; tT: (d, n).
// Full 8192-pt FFT conv: fwd stage h=4096 fused into load, radix-16 trips
// A(2048..256) B(128..16), MID(fwd 8..1 + That* + inv 1..8), D(16..128)
// E(256..2048), inv h=4096 fused into store (lower 4096 outputs kept).
//
// Occupancy geometry (the R3/R5 lesson): the register allocator targets the
// LDS-derived occupancy, and __launch_bounds__'s 2nd arg can only RAISE it.
// 64 KiB LDS -> 2 blocks/CU -> 4 waves/SIMD -> 128-VGPR cap -> ~1 GB spills.
// Fix: pad LDS to 96 KiB so only 1 block/CU fits (8 waves/CU = 2 waves/SIMD
// -> 256-VGPR budget), plus amdgpu_waves_per_eu(2,2) to pin the target.
// Live set ~150 VGPR < 256 -> no spill.
__global__ __attribute__((amdgpu_waves_per_eu(2, 2))) __launch_bounds__(NT)
void fftconv(float* __restrict__ xT, const float* __restrict__ tT) {
  __shared__ float2 cb[12288];   // 96 KiB declared; first 8192 used
  const int tid = threadIdx.x;
  const int d = blockIdx.x;

  const int rA = tid & 255;
  const int baseA = (tid >> 8) * 4096 + rA;   // trips A/E: G=256
  const int rB = tid & 15;
  const int baseB = (tid >> 4) * 256 + rB;    // trips B/D: G=16
  const int baseM = tid * 16;                 // MID: G=1

  float sa, ca; __sincosf(-PI_F * (float)rA / 2048.f, &sa, &ca);
  const float2 betaA  = make_float2(ca, sa);        // W_4096^rA
  const float2 gammaE = make_float2(ca, -sa);       // conj
  float sb, cbv; __sincosf(-PI_F * (float)rB / 128.f, &sb, &cbv);
  const float2 betaB  = make_float2(cbv, sb);       // W_256^rB
  const float2 gammaD = make_float2(cbv, -sb);      // conj

  const float2 ROT  = make_float2(C16x[1],  C16y[1]);  // e^{-i pi/8}  (NT=512 stride)
  const float2 ROTc = make_float2(C16x[1], -C16y[1]);  // e^{+i pi/8}
  float sw0, cw0; __sincosf(-PI_F * (float)tid / 4096.f, &sw0, &cw0);
  const float2 W0 = make_float2(cw0, sw0);   // e^{-i pi tid/4096}

  // ---- T-hat: load(+h=4096) -> A -> B -> final radix-16 kept in registers ----
  {
    const float* tp = tT + (size_t)d * 4096;
    float2 w = W0;
    #pragma unroll
    for (int k = 0; k < 8; ++k) {
      int n = tid + NT * k;
      float tv = tp[n];
      cb[P(n)] = make_float2(tv, 0.f);
      cb[P(n + 4096)] = make_float2(tv * w.x, tv * w.y);
      w = cmul(w, ROT);
    }
  }
  __syncthreads();
  trip_fwd(cb, baseA, 256, betaA); __syncthreads();
  trip_fwd(cb, baseB, 16, betaB);  __syncthreads();
  float2 Tr[16];
  {
    float2 e[16];
    #pragma unroll
    for (int j = 0; j < 16; ++j) e[j] = cb[P(baseM + j)];
    r16_fwd<true>(e, make_float2(1.f, 0.f));
    #pragma unroll
    for (int j = 0; j < 16; ++j) Tr[j] = make_float2(e[j].x * SCL, e[j].y * SCL);
  }
  __syncthreads();

  // ---- two complex passes: (x0 + i x1), (x2 + i x3); real filter ----
  #pragma unroll 1
  for (int pass = 0; pass < 2; ++pass) {
    float* r0 = xT + ((size_t)(2 * pass)     * 1024 + d) * 4096;
    float* r1 = xT + ((size_t)(2 * pass + 1) * 1024 + d) * 4096;
    {
      float2 w = W0;
      #pragma unroll
      for (int k = 0; k < 8; ++k) {
        int n = tid + NT * k;
        float2 v = make_float2(r0[n], r1[n]);
        cb[P(n)] = v;
        cb[P(n + 4096)] = cmul(v, w);
        w = cmul(w, ROT);
      }
    }
    __syncthreads();
    trip_fwd(cb, baseA, 256, betaA); __syncthreads();
    trip_fwd(cb, baseB, 16, betaB);  __syncthreads();
    {
      float2 e[16];
      #pragma unroll
      for (int j = 0; j < 16; ++j) e[j] = cb[P(baseM + j)];
      r16_fwd<true>(e, make_float2(1.f, 0.f));
      #pragma unroll
      for (int j = 0; j < 16; ++j) e[j] = cmul(e[j], Tr[j]);
      r16_inv<true>(e, make_float2(1.f, 0.f));
      #pragma unroll
      for (int j = 0; j < 16; ++j) cb[P(baseM + j)] = e[j];
    }
    __syncthreads();
    trip_inv(cb, baseB, 16, gammaD);  __syncthreads();
    trip_inv(cb, baseA, 256, gammaE); __syncthreads();
    {
      float2 w = make_float2(cw0, -sw0);   // e^{+i pi tid/4096}
      #pragma unroll
      for (int k = 0; k < 8; ++k) {
        int n = tid + NT * k;
        float2 u = cb[P(n)];
        float2 v = cmul(cb[P(n + 4096)], w);
        r0[n] = u.x + v.x;
        r1[n] = u.y + v.y;
        w = cmul(w, ROTc);
      }
    }
    __syncthreads();
  }
}

// 64x64 tile transpose, 256 threads, float4 global I/O, padded LDS.
__global__ __launch_bounds__(256)
void transpose64(const float* __restrict__ src, float* __restrict__ dst, int R, int C) {
  __shared__ float tile[64][65];
  int t  = threadIdx.x;
  int c4 = t & 15;
  int r  = t >> 4;
  size_t slab = (size_t)blockIdx.z * (size_t)R * (size_t)C;
  const float* s = src + slab;
  float* dd = dst + slab;
  int col0 = blockIdx.x * 64, row0 = blockIdx.y * 64;
  #pragma unroll
  for (int k = 0; k < 4; ++k) {
    int rr = r + 16 * k;
    const float4 v = *(const float4*)(s + (size_t)(row0 + rr) * C + col0 + 4 * c4);
    tile[rr][4 * c4 + 0] = v.x;
    tile[rr][4 * c4 + 1] = v.y;
    tile[rr][4 * c4 + 2] = v.z;
    tile[rr][4 * c4 + 3] = v.w;
  }
  __syncthreads();
  #pragma unroll
  for (int k = 0; k < 4; ++k) {
    int cc = r + 16 * k;
    float4 w;
    w.x = tile[4 * c4 + 0][cc];
    w.y = tile[4 * c4 + 1][cc];
    w.z = tile[4 * c4 + 2][cc];
    w.w = tile[4 * c4 + 3][cc];
    *(float4*)(dd + (size_t)(col0 + cc) * R + row0 + 4 * c4) = w;
  }
}

extern "C" void kernel_launch(void* const* d_in, const int* in_sizes, int n_in,
                              void* d_out, int out_size, void* d_ws, size_t ws_size,
                              hipStream_t stream) {
  const float* x = (const float*)d_in[0];   // (4, 4096, 1024)
  const float* t = (const float*)d_in[1];   // (4096, 1024)
  float* out = (float*)d_out;               // (4, 4096, 1024)
  float* ws  = (float*)d_ws;
  float* xT  = ws;                                   // (4, 1024, 4096)  64 MB
  float* tT  = ws + (size_t)4 * 1024 * 4096;         // (1024, 4096)     16 MB

  transpose64<<<dim3(16, 64, 4), 256, 0, stream>>>(x, xT, 4096, 1024);
  transpose64<<<dim3(16, 64, 1), 256, 0, stream>>>(t, tT, 4096, 1024);

  fftconv<<<dim3(1024), NT, 0, stream>>>(xT, tT);

  transpose64<<<dim3(64, 16, 4), 256, 0, stream>>>(xT, out, 1024, 4096);
}

// Round 7
// 183.271 us; speedup vs baseline: 2.2408x; 2.2408x over previous
//
#include <hip/hip_runtime.h>

#define NT 512
#define SCL (1.0f / 8192.0f)
#define PI_F 3.14159265358979323846f

// XOR swizzle: bijective involution on [0,8192); spreads the power-of-2 strided
// trip accesses across banks. Applied at EVERY cb/Th access.
__device__ __forceinline__ int P(int i) { return i ^ ((i >> 5) & 31); }

__device__ __forceinline__ float2 cmul(float2 a, float2 b) {
  return make_float2(a.x * b.x - a.y * b.y, a.x * b.y + a.y * b.x);
}
__device__ __forceinline__ float2 csqr(float2 a) {
  return make_float2(a.x * a.x - a.y * a.y, 2.f * a.x * a.y);
}
__device__ __forceinline__ float2 cadd(float2 a, float2 b) { return make_float2(a.x + b.x, a.y + b.y); }
__device__ __forceinline__ float2 csub(float2 a, float2 b) { return make_float2(a.x - b.x, a.y - b.y); }
__device__ __forceinline__ float2 cmuli (float2 a) { return make_float2(-a.y,  a.x); } // *(+i)
__device__ __forceinline__ float2 cmulmi(float2 a) { return make_float2( a.y, -a.x); } // *(-i)

constexpr float RT2 = 0.70710678118654752440f;
constexpr float CQ1 = 0.92387953251128675613f; // cos(pi/8)
constexpr float SQ1 = 0.38268343236508977173f; // sin(pi/8)
// C8[k] = W8^k = e^{-i pi k/4}
constexpr float C8x[4] = {1.f,  RT2, 0.f, -RT2};
constexpr float C8y[4] = {0.f, -RT2, -1.f, -RT2};

// In-register 8-point DIF, stages at register strides 4,2,1.
// Stage stride s uses twiddle b^{4/s} * W_{2s}^{j mod s}; UNIT means b == 1.
template<bool UNIT>
__device__ __forceinline__ void r8_fwd(float2* e, float2 b) {
  float2 b2, b4;
  if (!UNIT) { b2 = csqr(b); b4 = csqr(b2); }
  // s=4: tw = b * C8[j]
  #pragma unroll
  for (int j = 0; j < 4; ++j) {
    float2 u = e[j], v = e[j + 4];
    float2 d = csub(u, v);
    e[j] = cadd(u, v);
    float2 c8 = make_float2(C8x[j], C8y[j]);
    if (UNIT) e[j + 4] = (j == 0) ? d : cmul(d, c8);
    else      e[j + 4] = cmul(d, (j == 0) ? b : cmul(b, c8));
  }
  // s=2: tw = b2 * {1, -i}
  #pragma unroll
  for (int o = 0; o < 8; o += 4) {
    #pragma unroll
    for (int j = 0; j < 2; ++j) {
      float2 u = e[o + j], v = e[o + j + 2];
      float2 d = csub(u, v);
      e[o + j] = cadd(u, v);
      if (UNIT) e[o + j + 2] = (j == 0) ? d : cmulmi(d);
      else      e[o + j + 2] = cmul(d, (j == 0) ? b2 : cmulmi(b2));
    }
  }
  // s=1: tw = b4
  #pragma unroll
  for (int o = 0; o < 8; o += 2) {
    float2 u = e[o], v = e[o + 1];
    float2 d = csub(u, v);
    e[o] = cadd(u, v);
    e[o + 1] = UNIT ? d : cmul(d, b4);
  }
}

// In-register 8-point DIT inverse, stages at strides 1,2,4. g = conj(beta).
template<bool UNIT>
__device__ __forceinline__ void r8_inv(float2* e, float2 g) {
  float2 g2, g4;
  if (!UNIT) { g2 = csqr(g); g4 = csqr(g2); }
  // s=1: tw = g4
  #pragma unroll
  for (int o = 0; o < 8; o += 2) {
    float2 t = UNIT ? e[o + 1] : cmul(e[o + 1], g4);
    float2 u = e[o];
    e[o] = cadd(u, t); e[o + 1] = csub(u, t);
  }
  // s=2: tw = g2 * {1, +i}
  #pragma unroll
  for (int o = 0; o < 8; o += 4) {
    #pragma unroll
    for (int j = 0; j < 2; ++j) {
      float2 v = e[o + j + 2];
      float2 t;
      if (UNIT) t = (j == 0) ? v : cmuli(v);
      else      t = cmul(v, (j == 0) ? g2 : cmuli(g2));
      float2 u = e[o + j];
      e[o + j] = cadd(u, t); e[o + j + 2] = csub(u, t);
    }
  }
  // s=4: tw = g * conj(C8[j])
  #pragma unroll
  for (int j = 0; j < 4; ++j) {
    float2 v = e[j + 4];
    float2 t;
    float2 c8c = make_float2(C8x[j], -C8y[j]);
    if (UNIT) t = (j == 0) ? v : cmul(v, c8c);
    else      t = cmul(v, (j == 0) ? g : cmul(g, c8c));
    float2 u = e[j];
    e[j] = cadd(u, t); e[j + 4] = csub(u, t);
  }
}

// Each thread handles two radix-8 groups per trip: base and base+4096
// (same twiddle base for both, since the residue r is equal).
__device__ __forceinline__ void trip8_fwd(float2* cb, int base, int G, float2 b) {
  #pragma unroll 1
  for (int g = 0; g < 2; ++g) {
    int bs = base + g * 4096;
    float2 e[8];
    #pragma unroll
    for (int j = 0; j < 8; ++j) e[j] = cb[P(bs + G * j)];
    r8_fwd<false>(e, b);
    #pragma unroll
    for (int j = 0; j < 8; ++j) cb[P(bs + G * j)] = e[j];
  }
}

__device__ __forceinline__ void trip8_inv(float2* cb, int base, int G, float2 g) {
  #pragma unroll 1
  for (int gg = 0; gg < 2; ++gg) {
    int bs = base + gg * 4096;
    float2 e[8];
    #pragma unroll
    for (int j = 0; j < 8; ++j) e[j] = cb[P(bs + G * j)];
    r8_inv<false>(e, g);
    #pragma unroll
    for (int j = 0; j < 8; ++j) cb[P(bs + G * j)] = e[j];
  }
}

// One workgroup per channel d. xT: (b, d, n) rows of 4096; tT: (d, n).
// 8192-pt FFT conv, all radix-8 trips (R6 lesson: NT=512 has a hard 128-VGPR
// cap on this toolchain; radix-8 transient e[8]=16 VGPRs + T-hat in LDS (not
// registers) keeps peak live ~80 < 128 -> no scratch spills).
// Stages: load-fused h=4096, A(G=512: 2048,1024,512), B(G=64: 256,128,64),
// C(G=8: 32,16,8), MID(G=1: fwd 4,2,1 + That* + inv 1,2,4), D,E,F mirror,
// store-fused h=4096 (only lower 4096 outputs kept).
__global__ __launch_bounds__(NT)
void fftconv(float* __restrict__ xT, const float* __restrict__ tT) {
  __shared__ float2 cb[8192];   // 64 KiB working buffer
  __shared__ float2 Th[8192];   // 64 KiB T-hat (scaled), written once, read 2x
  const int tid = threadIdx.x;
  const int d = blockIdx.x;

  const int baseA = tid;                          // G=512
  const int baseB = ((tid >> 6) << 9) + (tid & 63); // G=64
  const int baseC = ((tid >> 3) << 6) + (tid & 7);  // G=8
  const int baseM = tid << 3;                       // G=1

  float s0, c0; __sincosf(-PI_F * (float)tid / 2048.f, &s0, &c0);
  const float2 bA = make_float2(c0, s0);            // W_4096^tid
  float s1, c1; __sincosf(-PI_F * (float)(tid & 63) / 256.f, &s1, &c1);
  const float2 bB = make_float2(c1, s1);            // W_512^(tid&63)
  float s2, c2; __sincosf(-PI_F * (float)(tid & 7) / 32.f, &s2, &c2);
  const float2 bC = make_float2(c2, s2);            // W_64^(tid&7)
  float sw, cw; __sincosf(-PI_F * (float)tid / 4096.f, &sw, &cw);
  const float2 W0 = make_float2(cw, sw);            // e^{-i pi tid/4096}
  const float2 ROT  = make_float2(CQ1, -SQ1);       // e^{-i pi/8}, step for n+=512
  const float2 ROTc = make_float2(CQ1,  SQ1);

  // ---- T-hat: load(+h=4096) -> A -> B -> C -> MID-fwd -> Th (scaled) ----
  {
    const float* tp = tT + (size_t)d * 4096;
    float2 w = W0;
    #pragma unroll
    for (int k = 0; k < 8; ++k) {
      int n = tid + NT * k;
      float tv = tp[n];
      cb[P(n)] = make_float2(tv, 0.f);
      cb[P(n + 4096)] = make_float2(tv * w.x, tv * w.y);
      w = cmul(w, ROT);
    }
  }
  __syncthreads();
  trip8_fwd(cb, baseA, 512, bA); __syncthreads();
  trip8_fwd(cb, baseB, 64,  bB); __syncthreads();
  trip8_fwd(cb, baseC, 8,   bC); __syncthreads();
  #pragma unroll 1
  for (int g = 0; g < 2; ++g) {
    int bs = baseM + g * 4096;
    float2 e[8];
    #pragma unroll
    for (int j = 0; j < 8; ++j) e[j] = cb[P(bs + j)];
    r8_fwd<true>(e, make_float2(1.f, 0.f));
    #pragma unroll
    for (int j = 0; j < 8; ++j) Th[P(bs + j)] = make_float2(e[j].x * SCL, e[j].y * SCL);
  }
  __syncthreads();

  // ---- two complex passes: (x0 + i x1), (x2 + i x3); real filter ----
  #pragma unroll 1
  for (int pass = 0; pass < 2; ++pass) {
    float* r0 = xT + ((size_t)(2 * pass)     * 1024 + d) * 4096;
    float* r1 = xT + ((size_t)(2 * pass + 1) * 1024 + d) * 4096;
    {
      float2 w = W0;
      #pragma unroll
      for (int k = 0; k < 8; ++k) {
        int n = tid + NT * k;
        float2 v = make_float2(r0[n], r1[n]);
        cb[P(n)] = v;
        cb[P(n + 4096)] = cmul(v, w);
        w = cmul(w, ROT);
      }
    }
    __syncthreads();
    trip8_fwd(cb, baseA, 512, bA); __syncthreads();
    trip8_fwd(cb, baseB, 64,  bB); __syncthreads();
    trip8_fwd(cb, baseC, 8,   bC); __syncthreads();
    #pragma unroll 1
    for (int g = 0; g < 2; ++g) {
      int bs = baseM + g * 4096;
      float2 e[8];
      #pragma unroll
      for (int j = 0; j < 8; ++j) e[j] = cb[P(bs + j)];
      r8_fwd<true>(e, make_float2(1.f, 0.f));
      #pragma unroll
      for (int j = 0; j < 8; ++j) e[j] = cmul(e[j], Th[P(bs + j)]);
      r8_inv<true>(e, make_float2(1.f, 0.f));
      #pragma unroll
      for (int j = 0; j < 8; ++j) cb[P(bs + j)] = e[j];
    }
    __syncthreads();
    trip8_inv(cb, baseC, 8,   make_float2(bC.x, -bC.y)); __syncthreads();
    trip8_inv(cb, baseB, 64,  make_float2(bB.x, -bB.y)); __syncthreads();
    trip8_inv(cb, baseA, 512, make_float2(bA.x, -bA.y)); __syncthreads();
    {
      float2 w = make_float2(cw, -sw);   // e^{+i pi tid/4096}
      #pragma unroll
      for (int k = 0; k < 8; ++k) {
        int n = tid + NT * k;
        float2 u = cb[P(n)];
        float2 v = cmul(cb[P(n + 4096)], w);
        r0[n] = u.x + v.x;
        r1[n] = u.y + v.y;
        w = cmul(w, ROTc);
      }
    }
    __syncthreads();
  }
}

// 64x64 tile transpose, 256 threads, float4 global I/O, padded LDS.
__global__ __launch_bounds__(256)
void transpose64(const float* __restrict__ src, float* __restrict__ dst, int R, int C) {
  __shared__ float tile[64][65];
  int t  = threadIdx.x;
  int c4 = t & 15;
  int r  = t >> 4;
  size_t slab = (size_t)blockIdx.z * (size_t)R * (size_t)C;
  const float* s = src + slab;
  float* dd = dst + slab;
  int col0 = blockIdx.x * 64, row0 = blockIdx.y * 64;
  #pragma unroll
  for (int k = 0; k < 4; ++k) {
    int rr = r + 16 * k;
    const float4 v = *(const float4*)(s + (size_t)(row0 + rr) * C + col0 + 4 * c4);
    tile[rr][4 * c4 + 0] = v.x;
    tile[rr][4 * c4 + 1] = v.y;
    tile[rr][4 * c4 + 2] = v.z;
    tile[rr][4 * c4 + 3] = v.w;
  }
  __syncthreads();
  #pragma unroll
  for (int k = 0; k < 4; ++k) {
    int cc = r + 16 * k;
    float4 w;
    w.x = tile[4 * c4 + 0][cc];
    w.y = tile[4 * c4 + 1][cc];
    w.z = tile[4 * c4 + 2][cc];
    w.w = tile[4 * c4 + 3][cc];
    *(float4*)(dd + (size_t)(col0 + cc) * R + row0 + 4 * c4) = w;
  }
}

extern "C" void kernel_launch(void* const* d_in, const int* in_sizes, int n_in,
                              void* d_out, int out_size, void* d_ws, size_t ws_size,
                              hipStream_t stream) {
  const float* x = (const float*)d_in[0];   // (4, 4096, 1024)
  const float* t = (const float*)d_in[1];   // (4096, 1024)
  float* out = (float*)d_out;               // (4, 4096, 1024)
  float* ws  = (float*)d_ws;
  float* xT  = ws;                                   // (4, 1024, 4096)  64 MB
  float* tT  = ws + (size_t)4 * 1024 * 4096;         // (1024, 4096)     16 MB

  transpose64<<<dim3(16, 64, 4), 256, 0, stream>>>(x, xT, 4096, 1024);
  transpose64<<<dim3(16, 64, 1), 256, 0, stream>>>(t, tT, 4096, 1024);

  fftconv<<<dim3(1024), NT, 0, stream>>>(xT, tT);

  transpose64<<<dim3(64, 16, 4), 256, 0, stream>>>(xT, out, 1024, 4096);
}